// Round 1
// baseline (387.341 us; speedup 1.0000x reference)
//
#include <hip/hip_runtime.h>
#include <math.h>

// Shapes fixed by setup_inputs(): x[8, 4096, 1024] fp32, output same.
#define Bb 8
#define Tt 4096
#define Dd 1024
#define EPSf 1e-5f
#define EPSVARf 1e-4f

// tanh(y) = 1 - 2/(exp(2y)+1); saturates correctly for |y| large (exp->inf or 0)
__device__ __forceinline__ float fast_tanh(float y) {
    float e = __expf(2.0f * y);
    return 1.0f - __fdividef(2.0f, e + 1.0f);
}

__device__ __forceinline__ float gelu1(float v) {
    float u = 0.7978845608028654f * fmaf(0.044715f * v, v * v, v);
    return 0.5f * v * (1.0f + fast_tanh(u));
}

// ---------------- prep: scalar params + per-d z1 constants -------------------
__global__ __launch_bounds__(1024) void prep_kernel(
    const float* __restrict__ ema_mean, const float* __restrict__ ema_sq,
    const float* __restrict__ ema_out, const float* __restrict__ var_fast,
    const float* __restrict__ var_slow,
    const float* __restrict__ p_log_tau, const float* __restrict__ p_log_sig1,
    const float* __restrict__ p_log_sig2, const float* __restrict__ p_log_sig3,
    const float* __restrict__ p_log_w, const float* __restrict__ p_log_a1,
    const float* __restrict__ p_log_a2, const float* __restrict__ p_log_a3,
    float* __restrict__ scal, float* __restrict__ inv1, float* __restrict__ c1)
{
    int d = threadIdx.x;  // 1024 threads == D
    float m = ema_mean[d];
    float vg = fmaxf(ema_sq[d] - m * m, EPSVARf);
    float ivd = 1.0f / (sqrtf(vg) + EPSf);
    inv1[d] = ivd;
    c1[d] = m * ivd;

    float br = fminf(var_fast[d] / fmaxf(var_slow[d], EPSVARf), 10.0f);
    float e = ema_out[d];

    __shared__ float sb[1024];
    __shared__ float se[1024];
    sb[d] = br;
    se[d] = e * e;
    __syncthreads();
    for (int off = 512; off > 0; off >>= 1) {
        if (d < off) { sb[d] += sb[d + off]; se[d] += se[d + off]; }
        __syncthreads();
    }
    if (d == 0) {
        float tau  = expf(p_log_tau[0]);
        float sig1 = log1pf(expf(p_log_sig1[0]));
        float sig2 = log1pf(expf(p_log_sig2[0]));
        float sig3 = log1pf(expf(p_log_sig3[0]));
        float w    = log1pf(expf(p_log_w[0]));
        float a1   = log1pf(expf(p_log_a1[0]));
        float a2   = log1pf(expf(p_log_a2[0]));
        float a3   = log1pf(expf(p_log_a3[0]));
        float burst = fmaxf(sb[0] / (float)Dd - 1.0f, 0.0f);
        float surp2 = tanhf(sig2 * burst);
        float s2p   = powf(fmaxf(surp2, 1e-7f), a2);
        scal[0] = sig1 / (float)Dd;              // k1
        scal[1] = sig3 / (float)Dd;              // k3
        scal[2] = tau;
        scal[3] = w;
        scal[4] = a1;
        scal[5] = a3;
        scal[6] = s2p;                           // surp2^a2 (scalar factor)
        scal[7] = 1.0f / fmaxf(sqrtf(se[0]), 1e-12f);  // 1/||ema_out||
    }
}

// ---------------- pass A: per-segment sums of x and x^2 ----------------------
__global__ __launch_bounds__(256) void seg_sum_kernel(
    const float* __restrict__ x, float* __restrict__ segx,
    float* __restrict__ segs, int nseg, int segt)
{
    int b = blockIdx.x / nseg, seg = blockIdx.x % nseg;
    int d0 = threadIdx.x * 4;
    const float* xr = x + ((size_t)b * Tt + (size_t)seg * segt) * Dd + d0;
    float4 sx = make_float4(0.f, 0.f, 0.f, 0.f);
    float4 ss = make_float4(0.f, 0.f, 0.f, 0.f);
    for (int i = 0; i < segt; ++i) {
        float4 v = *(const float4*)xr;
        sx.x += v.x; sx.y += v.y; sx.z += v.z; sx.w += v.w;
        ss.x = fmaf(v.x, v.x, ss.x); ss.y = fmaf(v.y, v.y, ss.y);
        ss.z = fmaf(v.z, v.z, ss.z); ss.w = fmaf(v.w, v.w, ss.w);
        xr += Dd;
    }
    size_t o = ((size_t)(b * nseg + seg)) * Dd + d0;
    *(float4*)(segx + o) = sx;
    *(float4*)(segs + o) = ss;
}

// ---------------- pass B: exclusive scan over segments (in place) ------------
__global__ __launch_bounds__(256) void seg_scan_kernel(
    float* __restrict__ segx, float* __restrict__ segs, int nseg)
{
    int idx = blockIdx.x * 256 + threadIdx.x;  // one thread per (b,d) column
    if (idx >= Bb * Dd) return;
    int b = idx >> 10;
    int d = idx & 1023;
    size_t base = (size_t)b * nseg * Dd + d;
    float ax = 0.f, as = 0.f;
    for (int s = 0; s < nseg; ++s) {
        size_t o = base + (size_t)s * Dd;
        float vx = segx[o], vs = segs[o];
        segx[o] = ax; segs[o] = as;
        ax += vx; as += vs;
    }
}

// ---------------- pass C: fused z1/z3/gelu row-reduce + gate + write ---------
// One block per (b, segment); 256 threads x float4 covers D=1024 exactly, so
// the per-t block reduction yields the complete row sums -> gate -> store.
__global__ __launch_bounds__(256, 4) void fused_main_kernel(
    const float* __restrict__ x, const float* __restrict__ ema_out,
    const float* __restrict__ scal, const float* __restrict__ inv1,
    const float* __restrict__ c1, const float* __restrict__ segx,
    const float* __restrict__ segs, float* __restrict__ out,
    int nseg, int segt)
{
    int b = blockIdx.x / nseg, seg = blockIdx.x % nseg;
    int tid = threadIdx.x;
    int d0 = tid * 4;
    int lane = tid & 63, wv = tid >> 6;

    float4 iv = *(const float4*)(inv1 + d0);
    float4 cc = *(const float4*)(c1 + d0);
    float4 eo = *(const float4*)(ema_out + d0);

    size_t so = ((size_t)(b * nseg + seg)) * Dd + d0;
    float4 rsx = *(const float4*)(segx + so);   // running sum x  (t' < t)
    float4 rss = *(const float4*)(segs + so);   // running sum x^2

    float k1 = scal[0], k3 = scal[1], tau = scal[2], w = scal[3];
    float a1 = scal[4], a3 = scal[5], s2p = scal[6], inv_en = scal[7];

    __shared__ float red[4][4];

    int t0 = seg * segt;
    const float* xr = x + ((size_t)b * Tt + t0) * Dd + d0;
    float* orow = out + ((size_t)b * Tt + t0) * Dd + d0;

    for (int i = 0; i < segt; ++i) {
        int t = t0 + i;
        float4 xv = *(const float4*)xr;

        // signal 1: |(x - mu_g)/(std_g+eps)| = |x*inv1 - c1|
        float p1 = fabsf(fmaf(xv.x, iv.x, -cc.x)) + fabsf(fmaf(xv.y, iv.y, -cc.y))
                 + fabsf(fmaf(xv.z, iv.z, -cc.z)) + fabsf(fmaf(xv.w, iv.w, -cc.w));

        // signal 3: causal cumulative z-score (t=0 forced to 0 per reference)
        float p3 = 0.f;
        if (t > 0) {
            float invt = __fdividef(1.0f, (float)t);
            float mux = rsx.x * invt, muy = rsx.y * invt;
            float muz = rsx.z * invt, muw = rsx.w * invt;
            float vx = fmaxf(fmaf(-mux, mux, rss.x * invt), EPSVARf);
            float vy = fmaxf(fmaf(-muy, muy, rss.y * invt), EPSVARf);
            float vz = fmaxf(fmaf(-muz, muz, rss.z * invt), EPSVARf);
            float vw = fmaxf(fmaf(-muw, muw, rss.w * invt), EPSVARf);
            p3 = fabsf(__fdividef(xv.x - mux, sqrtf(vx) + EPSf))
               + fabsf(__fdividef(xv.y - muy, sqrtf(vy) + EPSf))
               + fabsf(__fdividef(xv.z - muz, sqrtf(vz) + EPSf))
               + fabsf(__fdividef(xv.w - muw, sqrtf(vw) + EPSf));
        }

        // gelu + cosine-gate partials
        float gx = gelu1(xv.x), gy = gelu1(xv.y), gz = gelu1(xv.z), gw = gelu1(xv.w);
        float pg2 = gx * gx + gy * gy + gz * gz + gw * gw;
        float pge = gx * eo.x + gy * eo.y + gz * eo.z + gw * eo.w;

        // update running sums (after use: prefix is over t' < t)
        rsx.x += xv.x; rsx.y += xv.y; rsx.z += xv.z; rsx.w += xv.w;
        rss.x = fmaf(xv.x, xv.x, rss.x); rss.y = fmaf(xv.y, xv.y, rss.y);
        rss.z = fmaf(xv.z, xv.z, rss.z); rss.w = fmaf(xv.w, xv.w, rss.w);

        // block reduction of 4 row sums: wave shfl then LDS across 4 waves
        float v0 = p1, v1 = p3, v2 = pg2, v3 = pge;
        #pragma unroll
        for (int off = 32; off > 0; off >>= 1) {
            v0 += __shfl_down(v0, off);
            v1 += __shfl_down(v1, off);
            v2 += __shfl_down(v2, off);
            v3 += __shfl_down(v3, off);
        }
        __syncthreads();  // previous iteration's reads of red[] are done
        if (lane == 0) {
            red[wv][0] = v0; red[wv][1] = v1; red[wv][2] = v2; red[wv][3] = v3;
        }
        __syncthreads();
        float S1  = red[0][0] + red[1][0] + red[2][0] + red[3][0];
        float S3  = red[0][1] + red[1][1] + red[2][1] + red[3][1];
        float Sg2 = red[0][2] + red[1][2] + red[2][2] + red[3][2];
        float Sge = red[0][3] + red[1][3] + red[2][3] + red[3][3];

        // gate (computed redundantly by all lanes — SIMD-parallel, no serialization)
        float surp1 = fast_tanh(k1 * S1);
        float surp3 = fast_tanh(k3 * S3);
        float p1p = __expf(a1 * __logf(fmaxf(surp1, 1e-7f)));
        float p3p = __expf(a3 * __logf(fmaxf(surp3, 1e-7f)));
        float joint = p1p * s2p * p3p;
        float cs = Sge * __fdividef(1.0f, fmaxf(sqrtf(Sg2), 1e-12f)) * inv_en;
        cs = fminf(fmaxf(cs, -1.0f), 1.0f);
        float gate = __expf(-tau * cs) * fmaf(w, joint, 1.0f);

        float4 ov;
        ov.x = gx * gate; ov.y = gy * gate; ov.z = gz * gate; ov.w = gw * gate;
        *(float4*)orow = ov;

        xr += Dd; orow += Dd;
    }
}

// ----------------------------------------------------------------------------
extern "C" void kernel_launch(void* const* d_in, const int* in_sizes, int n_in,
                              void* d_out, int out_size, void* d_ws, size_t ws_size,
                              hipStream_t stream) {
    const float* x        = (const float*)d_in[0];
    const float* ema_mean = (const float*)d_in[1];
    const float* ema_sq   = (const float*)d_in[2];
    const float* ema_out  = (const float*)d_in[3];
    const float* var_fast = (const float*)d_in[4];
    const float* var_slow = (const float*)d_in[5];
    const float* log_tau  = (const float*)d_in[6];
    const float* log_sig1 = (const float*)d_in[7];
    const float* log_sig2 = (const float*)d_in[8];
    const float* log_sig3 = (const float*)d_in[9];
    const float* log_w    = (const float*)d_in[10];
    const float* log_a1   = (const float*)d_in[11];
    const float* log_a2   = (const float*)d_in[12];
    const float* log_a3   = (const float*)d_in[13];
    float* out = (float*)d_out;

    // workspace layout (floats): [0..32) scalars, [32..1056) inv1, [1056..2080) c1,
    // [4096 ..) segx[B*nseg*D], then segs[B*nseg*D]
    float* ws   = (float*)d_ws;
    float* scal = ws;
    float* inv1 = ws + 32;
    float* c1   = ws + 32 + Dd;
    float* segx = ws + 4096;

    int nseg = 128;  // segments of T; pick largest that fits in ws
    while (nseg > 8) {
        size_t need = (4096 + 2 * (size_t)Bb * nseg * Dd) * sizeof(float);
        if (need <= ws_size) break;
        nseg >>= 1;
    }
    int segt = Tt / nseg;
    float* segs = segx + (size_t)Bb * nseg * Dd;

    prep_kernel<<<1, 1024, 0, stream>>>(
        ema_mean, ema_sq, ema_out, var_fast, var_slow,
        log_tau, log_sig1, log_sig2, log_sig3, log_w, log_a1, log_a2, log_a3,
        scal, inv1, c1);

    seg_sum_kernel<<<Bb * nseg, 256, 0, stream>>>(x, segx, segs, nseg, segt);

    seg_scan_kernel<<<(Bb * Dd + 255) / 256, 256, 0, stream>>>(segx, segs, nseg);

    fused_main_kernel<<<Bb * nseg, 256, 0, stream>>>(
        x, ema_out, scal, inv1, c1, segx, segs, out, nseg, segt);
}

// Round 2
// 310.648 us; speedup vs baseline: 1.2469x; 1.2469x over previous
//
#include <hip/hip_runtime.h>
#include <math.h>

// Shapes fixed by setup_inputs(): x[8, 4096, 1024] fp32, output same.
#define Bb 8
#define Tt 4096
#define Dd 1024
#define EPSf 1e-5f
#define EPSVARf 1e-4f

// tanh(y) = 1 - 2/(exp(2y)+1); saturates correctly for |y| large
__device__ __forceinline__ float fast_tanh(float y) {
    float e = __expf(2.0f * y);
    return fmaf(-2.0f, __builtin_amdgcn_rcpf(e + 1.0f), 1.0f);
}

// ---------------- prep: scalar params + per-d z1 constants -------------------
__global__ __launch_bounds__(1024) void prep_kernel(
    const float* __restrict__ ema_mean, const float* __restrict__ ema_sq,
    const float* __restrict__ ema_out, const float* __restrict__ var_fast,
    const float* __restrict__ var_slow,
    const float* __restrict__ p_log_tau, const float* __restrict__ p_log_sig1,
    const float* __restrict__ p_log_sig2, const float* __restrict__ p_log_sig3,
    const float* __restrict__ p_log_w, const float* __restrict__ p_log_a1,
    const float* __restrict__ p_log_a2, const float* __restrict__ p_log_a3,
    float* __restrict__ scal, float* __restrict__ inv1, float* __restrict__ c1)
{
    int d = threadIdx.x;  // 1024 threads == D
    float m = ema_mean[d];
    float vg = fmaxf(ema_sq[d] - m * m, EPSVARf);
    float ivd = 1.0f / (sqrtf(vg) + EPSf);
    inv1[d] = ivd;
    c1[d] = m * ivd;

    float br = fminf(var_fast[d] / fmaxf(var_slow[d], EPSVARf), 10.0f);
    float e = ema_out[d];

    __shared__ float sb[1024];
    __shared__ float se[1024];
    sb[d] = br;
    se[d] = e * e;
    __syncthreads();
    for (int off = 512; off > 0; off >>= 1) {
        if (d < off) { sb[d] += sb[d + off]; se[d] += se[d + off]; }
        __syncthreads();
    }
    if (d == 0) {
        float tau  = expf(p_log_tau[0]);
        float sig1 = log1pf(expf(p_log_sig1[0]));
        float sig2 = log1pf(expf(p_log_sig2[0]));
        float sig3 = log1pf(expf(p_log_sig3[0]));
        float w    = log1pf(expf(p_log_w[0]));
        float a1   = log1pf(expf(p_log_a1[0]));
        float a2   = log1pf(expf(p_log_a2[0]));
        float a3   = log1pf(expf(p_log_a3[0]));
        float burst = fmaxf(sb[0] / (float)Dd - 1.0f, 0.0f);
        float surp2 = tanhf(sig2 * burst);
        float s2p   = powf(fmaxf(surp2, 1e-7f), a2);
        scal[0] = sig1 / (float)Dd;              // k1
        scal[1] = sig3 / (float)Dd;              // k3
        scal[2] = tau;
        scal[3] = w;
        scal[4] = a1;
        scal[5] = a3;
        scal[6] = s2p;                           // surp2^a2 (scalar factor)
        scal[7] = 1.0f / fmaxf(sqrtf(se[0]), 1e-12f);  // 1/||ema_out||
    }
}

// ---------------- pass A: per-segment sums of x and x^2 ----------------------
template<int SEGT>
__global__ __launch_bounds__(256) void seg_sum_kernel(
    const float* __restrict__ x, float* __restrict__ segx,
    float* __restrict__ segs, int nseg)
{
    int b = blockIdx.x / nseg, seg = blockIdx.x - b * nseg;
    int d0 = threadIdx.x * 4;
    const float* xr = x + ((size_t)b * Tt + (size_t)seg * SEGT) * Dd + d0;
    float4 sx = make_float4(0.f, 0.f, 0.f, 0.f);
    float4 ss = make_float4(0.f, 0.f, 0.f, 0.f);
    for (int i = 0; i < SEGT; ++i) {
        float4 v = *(const float4*)xr;
        sx.x += v.x; sx.y += v.y; sx.z += v.z; sx.w += v.w;
        ss.x = fmaf(v.x, v.x, ss.x); ss.y = fmaf(v.y, v.y, ss.y);
        ss.z = fmaf(v.z, v.z, ss.z); ss.w = fmaf(v.w, v.w, ss.w);
        xr += Dd;
    }
    size_t o = ((size_t)(b * nseg + seg)) * Dd + d0;
    *(float4*)(segx + o) = sx;
    *(float4*)(segs + o) = ss;
}

// ---------------- pass B: parallel exclusive scan over segments --------------
// 8 sub-scanners per (b,d) column; LDS prefix across sub-scanners.
// Block = 256 threads = 32 columns x 8 sub-scanners. Grid = B*D/32 = 256.
template<int NSEG>
__global__ __launch_bounds__(256) void seg_scan_kernel(
    float* __restrict__ segx, float* __restrict__ segs)
{
    constexpr int K = 8;
    constexpr int COLS = 32;           // 256 / K
    constexpr int CH = NSEG / K;
    int tid = threadIdx.x;
    int col = tid & (COLS - 1);
    int q = tid >> 5;
    int gcol = blockIdx.x * COLS + col;   // 0 .. B*D-1
    int b = gcol >> 10, d = gcol & 1023;
    size_t base = (size_t)b * NSEG * Dd + d + (size_t)q * CH * Dd;

    // phase 1: sub-scan totals (read only)
    float ax = 0.f, as = 0.f;
    {
        const float* px = segx + base;
        const float* ps = segs + base;
        #pragma unroll 4
        for (int s = 0; s < CH; ++s) {
            ax += px[(size_t)s * Dd];
            as += ps[(size_t)s * Dd];
        }
    }
    __shared__ float lx[K][COLS], ls[K][COLS];
    lx[q][col] = ax; ls[q][col] = as;
    __syncthreads();
    float rx = 0.f, rs = 0.f;
    for (int r = 0; r < q; ++r) { rx += lx[r][col]; rs += ls[r][col]; }

    // phase 2: exclusive write with running prefix
    float* qx = segx + base;
    float* qs = segs + base;
    for (int s = 0; s < CH; ++s) {
        size_t o = (size_t)s * Dd;
        float vx = qx[o], vs = qs[o];
        qx[o] = rx; qs[o] = rs;
        rx += vx; rs += vs;
    }
}

// ---------------- pass C: wave-per-segment fused gate + write ----------------
// Each 64-lane wave owns one (b, segment); lane covers d = 4*lane + 256*j.
// No barriers, no LDS: row reduction is 6 shfl_xor rounds.
template<int SEGT>
__global__ __launch_bounds__(256) void fused_main_kernel(
    const float* __restrict__ x, const float* __restrict__ ema_out,
    const float* __restrict__ scal, const float* __restrict__ inv1,
    const float* __restrict__ c1, const float* __restrict__ segx,
    const float* __restrict__ segs, float* __restrict__ out, int nseg)
{
    int gw = (blockIdx.x * 256 + threadIdx.x) >> 6;   // global wave id
    int lane = threadIdx.x & 63;
    int b = gw / nseg, seg = gw - b * nseg;
    int d0 = lane * 4;

    float4 iv[4], cc[4], eo[4], rsx[4], rss[4];
    size_t so = ((size_t)(b * nseg + seg)) * Dd + d0;
    #pragma unroll
    for (int j = 0; j < 4; ++j) {
        iv[j]  = *(const float4*)(inv1 + d0 + 256 * j);
        cc[j]  = *(const float4*)(c1   + d0 + 256 * j);
        eo[j]  = *(const float4*)(ema_out + d0 + 256 * j);
        rsx[j] = *(const float4*)(segx + so + 256 * j);
        rss[j] = *(const float4*)(segs + so + 256 * j);
    }
    float k1 = scal[0], k3 = scal[1], tau = scal[2], w = scal[3];
    float a1 = scal[4], a3 = scal[5], s2p = scal[6], inv_en = scal[7];

    int t0 = seg * SEGT;
    const float* xr = x + ((size_t)b * Tt + t0) * Dd + d0;
    float* orow = out + ((size_t)b * Tt + t0) * Dd + d0;

    float4 xv[4];
    #pragma unroll
    for (int j = 0; j < 4; ++j) xv[j] = *(const float4*)(xr + 256 * j);

    #pragma unroll 1
    for (int i = 0; i < SEGT; ++i) {
        int t = t0 + i;
        float4 xn[4];
        if (i + 1 < SEGT) {      // prefetch next row (wave-uniform branch)
            #pragma unroll
            for (int j = 0; j < 4; ++j) xn[j] = *(const float4*)(xr + Dd + 256 * j);
        }

        float p1 = 0.f, p3 = 0.f, pg2 = 0.f, pge = 0.f;
        float4 g[4];
        float invt = (t > 0) ? __builtin_amdgcn_rcpf((float)t) : 0.0f;

#define COMP(J, C) { \
        float xvv = xv[J].C; \
        p1 += fabsf(fmaf(xvv, iv[J].C, -cc[J].C)); \
        float mu = rsx[J].C * invt; \
        float vr = fmaxf(fmaf(-mu, mu, rss[J].C * invt), EPSVARf); \
        float r  = __builtin_amdgcn_rsqf(vr); \
        float ri = r * fmaf(-EPSf, r, 1.0f); \
        p3 += fabsf((xvv - mu) * ri); \
        float xx = xvv * xvv; \
        float u2 = xvv * fmaf(0.07135481628f, xx, 1.59576912161f); \
        float e  = __expf(u2); \
        float th = fmaf(-2.0f, __builtin_amdgcn_rcpf(e + 1.0f), 1.0f); \
        float hx = 0.5f * xvv; \
        float gg = fmaf(hx, th, hx); \
        g[J].C = gg; \
        pg2 = fmaf(gg, gg, pg2); \
        pge = fmaf(gg, eo[J].C, pge); \
        rsx[J].C += xvv; \
        rss[J].C = fmaf(xvv, xvv, rss[J].C); \
    }
        #pragma unroll
        for (int j = 0; j < 4; ++j) { COMP(j, x) COMP(j, y) COMP(j, z) COMP(j, w) }
#undef COMP
        if (t == 0) p3 = 0.f;   // reference forces z3[:,0,:] = 0

        // wave-wide butterfly reduction (all lanes end with totals)
        #pragma unroll
        for (int off = 32; off > 0; off >>= 1) {
            p1  += __shfl_xor(p1,  off);
            p3  += __shfl_xor(p3,  off);
            pg2 += __shfl_xor(pg2, off);
            pge += __shfl_xor(pge, off);
        }

        float surp1 = fast_tanh(k1 * p1);
        float surp3 = fast_tanh(k3 * p3);
        float lg = fmaf(a1, __logf(fmaxf(surp1, 1e-7f)),
                        a3 * __logf(fmaxf(surp3, 1e-7f)));
        float joint = __expf(lg) * s2p;
        float rg = __builtin_amdgcn_rsqf(fmaxf(pg2, 1e-24f));
        float cs = fminf(fmaxf(pge * rg * inv_en, -1.0f), 1.0f);
        float gate = __expf(-tau * cs) * fmaf(w, joint, 1.0f);

        #pragma unroll
        for (int j = 0; j < 4; ++j) {
            float4 ov;
            ov.x = g[j].x * gate; ov.y = g[j].y * gate;
            ov.z = g[j].z * gate; ov.w = g[j].w * gate;
            *(float4*)(orow + 256 * j) = ov;
        }
        #pragma unroll
        for (int j = 0; j < 4; ++j) xv[j] = xn[j];
        xr += Dd; orow += Dd;
    }
}

// ----------------------------------------------------------------------------
extern "C" void kernel_launch(void* const* d_in, const int* in_sizes, int n_in,
                              void* d_out, int out_size, void* d_ws, size_t ws_size,
                              hipStream_t stream) {
    const float* x        = (const float*)d_in[0];
    const float* ema_mean = (const float*)d_in[1];
    const float* ema_sq   = (const float*)d_in[2];
    const float* ema_out  = (const float*)d_in[3];
    const float* var_fast = (const float*)d_in[4];
    const float* var_slow = (const float*)d_in[5];
    const float* log_tau  = (const float*)d_in[6];
    const float* log_sig1 = (const float*)d_in[7];
    const float* log_sig2 = (const float*)d_in[8];
    const float* log_sig3 = (const float*)d_in[9];
    const float* log_w    = (const float*)d_in[10];
    const float* log_a1   = (const float*)d_in[11];
    const float* log_a2   = (const float*)d_in[12];
    const float* log_a3   = (const float*)d_in[13];
    float* out = (float*)d_out;

    // ws layout (floats): [0..32) scalars, [32..1056) inv1, [1056..2080) c1,
    // [4096..) segx[B*nseg*D], then segs[B*nseg*D]
    float* ws   = (float*)d_ws;
    float* scal = ws;
    float* inv1 = ws + 32;
    float* c1   = ws + 32 + Dd;
    float* segx = ws + 4096;

    int nseg = 256;
    while (nseg > 64) {
        size_t need = (4096 + 2 * (size_t)Bb * nseg * Dd) * sizeof(float);
        if (need <= ws_size) break;
        nseg >>= 1;
    }
    float* segs = segx + (size_t)Bb * nseg * Dd;

    prep_kernel<<<1, 1024, 0, stream>>>(
        ema_mean, ema_sq, ema_out, var_fast, var_slow,
        log_tau, log_sig1, log_sig2, log_sig3, log_w, log_a1, log_a2, log_a3,
        scal, inv1, c1);

    int fused_blocks = Bb * nseg / 4;   // 4 waves per 256-thread block
    if (nseg == 256) {
        seg_sum_kernel<16><<<Bb * nseg, 256, 0, stream>>>(x, segx, segs, nseg);
        seg_scan_kernel<256><<<Bb * Dd / 32, 256, 0, stream>>>(segx, segs);
        fused_main_kernel<16><<<fused_blocks, 256, 0, stream>>>(
            x, ema_out, scal, inv1, c1, segx, segs, out, nseg);
    } else if (nseg == 128) {
        seg_sum_kernel<32><<<Bb * nseg, 256, 0, stream>>>(x, segx, segs, nseg);
        seg_scan_kernel<128><<<Bb * Dd / 32, 256, 0, stream>>>(segx, segs);
        fused_main_kernel<32><<<fused_blocks, 256, 0, stream>>>(
            x, ema_out, scal, inv1, c1, segx, segs, out, nseg);
    } else {
        seg_sum_kernel<64><<<Bb * nseg, 256, 0, stream>>>(x, segx, segs, nseg);
        seg_scan_kernel<64><<<Bb * Dd / 32, 256, 0, stream>>>(segx, segs);
        fused_main_kernel<64><<<fused_blocks, 256, 0, stream>>>(
            x, ema_out, scal, inv1, c1, segx, segs, out, nseg);
    }
}

// Round 3
// 307.608 us; speedup vs baseline: 1.2592x; 1.0099x over previous
//
#include <hip/hip_runtime.h>
#include <math.h>

// Shapes fixed by setup_inputs(): x[8, 4096, 1024] fp32, output same.
#define Bb 8
#define Tt 4096
#define Dd 1024
#define EPSf 1e-5f
#define EPSVARf 1e-4f
#define NSEG 256          // segments per (b) along T
#define SEGT (Tt / NSEG)  // 16 rows per segment

// tanh(y) = 1 - 2/(exp(2y)+1); saturates correctly for |y| large
__device__ __forceinline__ float fast_tanh(float y) {
    float e = __expf(2.0f * y);
    return fmaf(-2.0f, __builtin_amdgcn_rcpf(e + 1.0f), 1.0f);
}

// ---------------- prep: scalar params + per-d z1 constants -------------------
__global__ __launch_bounds__(1024) void prep_kernel(
    const float* __restrict__ ema_mean, const float* __restrict__ ema_sq,
    const float* __restrict__ ema_out, const float* __restrict__ var_fast,
    const float* __restrict__ var_slow,
    const float* __restrict__ p_log_tau, const float* __restrict__ p_log_sig1,
    const float* __restrict__ p_log_sig2, const float* __restrict__ p_log_sig3,
    const float* __restrict__ p_log_w, const float* __restrict__ p_log_a1,
    const float* __restrict__ p_log_a2, const float* __restrict__ p_log_a3,
    float* __restrict__ scal, float* __restrict__ inv1, float* __restrict__ c1)
{
    int d = threadIdx.x;  // 1024 threads == D
    float m = ema_mean[d];
    float vg = fmaxf(ema_sq[d] - m * m, EPSVARf);
    float ivd = 1.0f / (sqrtf(vg) + EPSf);
    inv1[d] = ivd;
    c1[d] = m * ivd;

    float br = fminf(var_fast[d] / fmaxf(var_slow[d], EPSVARf), 10.0f);
    float e = ema_out[d];

    __shared__ float sb[1024];
    __shared__ float se[1024];
    sb[d] = br;
    se[d] = e * e;
    __syncthreads();
    for (int off = 512; off > 0; off >>= 1) {
        if (d < off) { sb[d] += sb[d + off]; se[d] += se[d + off]; }
        __syncthreads();
    }
    if (d == 0) {
        float tau  = expf(p_log_tau[0]);
        float sig1 = log1pf(expf(p_log_sig1[0]));
        float sig2 = log1pf(expf(p_log_sig2[0]));
        float sig3 = log1pf(expf(p_log_sig3[0]));
        float w    = log1pf(expf(p_log_w[0]));
        float a1   = log1pf(expf(p_log_a1[0]));
        float a2   = log1pf(expf(p_log_a2[0]));
        float a3   = log1pf(expf(p_log_a3[0]));
        float burst = fmaxf(sb[0] / (float)Dd - 1.0f, 0.0f);
        float surp2 = tanhf(sig2 * burst);
        float s2p   = powf(fmaxf(surp2, 1e-7f), a2);
        scal[0] = sig1 / (float)Dd;              // k1
        scal[1] = sig3 / (float)Dd;              // k3
        scal[2] = tau;
        scal[3] = w;
        scal[4] = a1;
        scal[5] = a3;
        scal[6] = s2p;                           // surp2^a2 (scalar factor)
        scal[7] = 1.0f / fmaxf(sqrtf(se[0]), 1e-12f);  // 1/||ema_out||
    }
}

// ---------------- pass 1: wave-per-segment ----------------------------------
// Computes (a) interleaved segment totals (sum x, sum x^2) for the scan, and
// (b) per-row gate constants A = gate_cos, B = gate_cos*w*s1^a1*s2^a2, so the
// final pass only needs signal 3. Barrier-free: 64-lane wave owns full D row.
__global__ __launch_bounds__(256) void pass1_kernel(
    const float* __restrict__ x, const float* __restrict__ ema_out,
    const float* __restrict__ scal, const float* __restrict__ inv1,
    const float* __restrict__ c1, float* __restrict__ rowc,
    float* __restrict__ segp)
{
    int gw = (blockIdx.x * 256 + threadIdx.x) >> 6;
    int lane = threadIdx.x & 63;
    int b = gw >> 8, seg = gw & (NSEG - 1);
    int d0 = lane * 4;

    float4 iv[4], cc[4], eo[4];
    #pragma unroll
    for (int j = 0; j < 4; ++j) {
        iv[j] = *(const float4*)(inv1 + d0 + 256 * j);
        cc[j] = *(const float4*)(c1 + d0 + 256 * j);
        eo[j] = *(const float4*)(ema_out + d0 + 256 * j);
    }
    float k1 = scal[0], tau = scal[2], w = scal[3], a1 = scal[4];
    float s2p = scal[6], inv_en = scal[7];

    float4 rsx[4] = {{0,0,0,0},{0,0,0,0},{0,0,0,0},{0,0,0,0}};
    float4 rss[4] = {{0,0,0,0},{0,0,0,0},{0,0,0,0},{0,0,0,0}};

    int t0 = seg * SEGT;
    const float* xr = x + ((size_t)b * Tt + t0) * Dd + d0;
    float* rc = rowc + ((size_t)b * Tt + t0) * 2;

    float4 xv[4];
    #pragma unroll
    for (int j = 0; j < 4; ++j) xv[j] = *(const float4*)(xr + 256 * j);

    #pragma unroll 1
    for (int i = 0; i < SEGT; ++i) {
        float4 xn[4];
        if (i + 1 < SEGT) {
            #pragma unroll
            for (int j = 0; j < 4; ++j) xn[j] = *(const float4*)(xr + Dd + 256 * j);
        }
        float p1 = 0.f, pg2 = 0.f, pge = 0.f;

#define COMP(J, C) { \
        float xvv = xv[J].C; \
        p1 += fabsf(fmaf(xvv, iv[J].C, -cc[J].C)); \
        float xx = xvv * xvv; \
        float u2 = xvv * fmaf(0.07135481628f, xx, 1.59576912161f); \
        float e  = __expf(u2); \
        float th = fmaf(-2.0f, __builtin_amdgcn_rcpf(e + 1.0f), 1.0f); \
        float hx = 0.5f * xvv; \
        float gg = fmaf(hx, th, hx); \
        pg2 = fmaf(gg, gg, pg2); \
        pge = fmaf(gg, eo[J].C, pge); \
        rsx[J].C += xvv; \
        rss[J].C = fmaf(xvv, xvv, rss[J].C); \
    }
        #pragma unroll
        for (int j = 0; j < 4; ++j) { COMP(j, x) COMP(j, y) COMP(j, z) COMP(j, w) }
#undef COMP

        #pragma unroll
        for (int off = 32; off > 0; off >>= 1) {
            p1  += __shfl_xor(p1,  off);
            pg2 += __shfl_xor(pg2, off);
            pge += __shfl_xor(pge, off);
        }
        // per-row gate constants (all lanes compute; lane 0 stores)
        float surp1 = fast_tanh(k1 * p1);
        float s1p = __expf(a1 * __logf(fmaxf(surp1, 1e-7f)));
        float rg = __builtin_amdgcn_rsqf(fmaxf(pg2, 1e-24f));
        float cs = fminf(fmaxf(pge * rg * inv_en, -1.0f), 1.0f);
        float A = __expf(-tau * cs);
        float Bv = A * w * s1p * s2p;
        if (lane == 0) { rc[0] = A; rc[1] = Bv; }

        #pragma unroll
        for (int j = 0; j < 4; ++j) xv[j] = xn[j];
        xr += Dd; rc += 2;
    }

    // interleaved segment totals: (sx,ss) pairs, 32 B contiguous per lane
    float* sp = segp + ((size_t)(b * NSEG + seg) * Dd + d0) * 2;
    #pragma unroll
    for (int j = 0; j < 4; ++j) {
        float4 lo, hi;
        lo.x = rsx[j].x; lo.y = rss[j].x; lo.z = rsx[j].y; lo.w = rss[j].y;
        hi.x = rsx[j].z; hi.y = rss[j].z; hi.z = rsx[j].w; hi.w = rss[j].w;
        *(float4*)(sp + 512 * j) = lo;
        *(float4*)(sp + 512 * j + 4) = hi;
    }
}

// ---------------- pass 2: parallel exclusive scan over segments --------------
// 8 sub-scanners per (b,d) column on interleaved float2 (sx,ss) pairs.
__global__ __launch_bounds__(256) void seg_scan_kernel(float2* __restrict__ segp)
{
    constexpr int K = 8;
    constexpr int COLS = 32;
    constexpr int CH = NSEG / K;       // 32
    int tid = threadIdx.x;
    int col = tid & (COLS - 1);
    int q = tid >> 5;
    int gcol = blockIdx.x * COLS + col;   // 0 .. B*D-1
    int b = gcol >> 10, d = gcol & 1023;
    float2* p = segp + ((size_t)b * NSEG + (size_t)q * CH) * Dd + d;

    // phase 1: sub-chain totals
    float ax = 0.f, as = 0.f;
    #pragma unroll 4
    for (int s = 0; s < CH; ++s) {
        float2 v = p[(size_t)s * Dd];
        ax += v.x; as += v.y;
    }
    __shared__ float lx[K][COLS], ls[K][COLS];
    lx[q][col] = ax; ls[q][col] = as;
    __syncthreads();
    float rx = 0.f, rs = 0.f;
    for (int r = 0; r < q; ++r) { rx += lx[r][col]; rs += ls[r][col]; }

    // phase 2: exclusive write with running prefix
    for (int s = 0; s < CH; ++s) {
        size_t o = (size_t)s * Dd;
        float2 v = p[o];
        float2 e; e.x = rx; e.y = rs;
        p[o] = e;
        rx += v.x; rs += v.y;
    }
}

// ---------------- pass 3: signal-3 + gelu + gate + write ---------------------
// Wave-per-segment; only ONE butterfly chain per row; gate = A + B*s3^a3.
__global__ __launch_bounds__(256) void fused_main_kernel(
    const float* __restrict__ x, const float* __restrict__ scal,
    const float* __restrict__ rowc, const float* __restrict__ segp,
    float* __restrict__ out)
{
    int gw = (blockIdx.x * 256 + threadIdx.x) >> 6;
    int lane = threadIdx.x & 63;
    int b = gw >> 8, seg = gw & (NSEG - 1);
    int d0 = lane * 4;

    float4 rsx[4], rss[4];
    const float* sp = segp + ((size_t)(b * NSEG + seg) * Dd + d0) * 2;
    #pragma unroll
    for (int j = 0; j < 4; ++j) {
        float4 lo = *(const float4*)(sp + 512 * j);
        float4 hi = *(const float4*)(sp + 512 * j + 4);
        rsx[j].x = lo.x; rss[j].x = lo.y; rsx[j].y = lo.z; rss[j].y = lo.w;
        rsx[j].z = hi.x; rss[j].z = hi.y; rsx[j].w = hi.z; rss[j].w = hi.w;
    }
    float k3 = scal[1], a3 = scal[5];

    int t0 = seg * SEGT;
    const float* xr = x + ((size_t)b * Tt + t0) * Dd + d0;
    const float* rc = rowc + ((size_t)b * Tt + t0) * 2;
    float* orow = out + ((size_t)b * Tt + t0) * Dd + d0;

    float4 xv[4];
    #pragma unroll
    for (int j = 0; j < 4; ++j) xv[j] = *(const float4*)(xr + 256 * j);

    #pragma unroll 1
    for (int i = 0; i < SEGT; ++i) {
        int t = t0 + i;
        float4 xn[4];
        if (i + 1 < SEGT) {
            #pragma unroll
            for (int j = 0; j < 4; ++j) xn[j] = *(const float4*)(xr + Dd + 256 * j);
        }
        float2 ab = *(const float2*)rc;   // wave-uniform broadcast load

        float p3 = 0.f;
        float4 g[4];
        float invt = (t > 0) ? __builtin_amdgcn_rcpf((float)t) : 0.0f;

#define COMP(J, C) { \
        float xvv = xv[J].C; \
        float mu = rsx[J].C * invt; \
        float vr = fmaxf(fmaf(-mu, mu, rss[J].C * invt), EPSVARf); \
        float r  = __builtin_amdgcn_rsqf(vr); \
        float ri = r * fmaf(-EPSf, r, 1.0f); \
        p3 += fabsf((xvv - mu) * ri); \
        float xx = xvv * xvv; \
        float u2 = xvv * fmaf(0.07135481628f, xx, 1.59576912161f); \
        float e  = __expf(u2); \
        float th = fmaf(-2.0f, __builtin_amdgcn_rcpf(e + 1.0f), 1.0f); \
        float hx = 0.5f * xvv; \
        g[J].C = fmaf(hx, th, hx); \
        rsx[J].C += xvv; \
        rss[J].C = fmaf(xvv, xvv, rss[J].C); \
    }
        #pragma unroll
        for (int j = 0; j < 4; ++j) { COMP(j, x) COMP(j, y) COMP(j, z) COMP(j, w) }
#undef COMP
        if (t == 0) p3 = 0.f;   // reference forces z3[:,0,:] = 0

        #pragma unroll
        for (int off = 32; off > 0; off >>= 1) p3 += __shfl_xor(p3, off);

        float surp3 = fast_tanh(k3 * p3);
        float s3p = __expf(a3 * __logf(fmaxf(surp3, 1e-7f)));
        float gate = fmaf(ab.y, s3p, ab.x);

        #pragma unroll
        for (int j = 0; j < 4; ++j) {
            float4 ov;
            ov.x = g[j].x * gate; ov.y = g[j].y * gate;
            ov.z = g[j].z * gate; ov.w = g[j].w * gate;
            *(float4*)(orow + 256 * j) = ov;
        }
        #pragma unroll
        for (int j = 0; j < 4; ++j) xv[j] = xn[j];
        xr += Dd; rc += 2; orow += Dd;
    }
}

// ----------------------------------------------------------------------------
extern "C" void kernel_launch(void* const* d_in, const int* in_sizes, int n_in,
                              void* d_out, int out_size, void* d_ws, size_t ws_size,
                              hipStream_t stream) {
    const float* x        = (const float*)d_in[0];
    const float* ema_mean = (const float*)d_in[1];
    const float* ema_sq   = (const float*)d_in[2];
    const float* ema_out  = (const float*)d_in[3];
    const float* var_fast = (const float*)d_in[4];
    const float* var_slow = (const float*)d_in[5];
    const float* log_tau  = (const float*)d_in[6];
    const float* log_sig1 = (const float*)d_in[7];
    const float* log_sig2 = (const float*)d_in[8];
    const float* log_sig3 = (const float*)d_in[9];
    const float* log_w    = (const float*)d_in[10];
    const float* log_a1   = (const float*)d_in[11];
    const float* log_a2   = (const float*)d_in[12];
    const float* log_a3   = (const float*)d_in[13];
    float* out = (float*)d_out;

    // ws layout (floats): [0..32) scalars, [32..1056) inv1, [1056..2080) c1,
    // [4096..4096+2*B*T) rowc(A,B per row), then segp interleaved (sx,ss):
    // 2*B*NSEG*D floats. Total ~17 MB (ws is 512 MiB).
    float* ws   = (float*)d_ws;
    float* scal = ws;
    float* inv1 = ws + 32;
    float* c1   = ws + 32 + Dd;
    float* rowc = ws + 4096;
    float* segp = rowc + 2 * (size_t)Bb * Tt;

    prep_kernel<<<1, 1024, 0, stream>>>(
        ema_mean, ema_sq, ema_out, var_fast, var_slow,
        log_tau, log_sig1, log_sig2, log_sig3, log_w, log_a1, log_a2, log_a3,
        scal, inv1, c1);

    pass1_kernel<<<Bb * NSEG / 4, 256, 0, stream>>>(
        x, ema_out, scal, inv1, c1, rowc, segp);

    seg_scan_kernel<<<Bb * Dd / 32, 256, 0, stream>>>((float2*)segp);

    fused_main_kernel<<<Bb * NSEG / 4, 256, 0, stream>>>(
        x, scal, rowc, segp, out);
}